// Round 5
// baseline (179.184 us; speedup 1.0000x reference)
//
#include <hip/hip_runtime.h>

// out[d] = sum_{e: dst[e]==d} x[src[e]]   (N=100k, E=1.6M, D=32 f32)
//
// Round-4 lesson: traffic is near-minimal but every phase is under-subscribed
// (hist/scatter: 196 blocks = 0.77 waves/SIMD; gather: 782 blocks = 26% occ,
// latency-bound at 22% HBM). Fix: CHUNK 8192->2048 (hist/scatter = 782 blocks)
// and split each gather bucket 4-way by node-quarter (3128 blocks, 12/CU);
// sub-blocks re-read the bucket's bin entries (L2-absorbed) but divide the
// expensive random x-row fetches exactly 4 ways.

#define D_FEAT 32
#define BKT_SHIFT 7
#define BKT_NODES 128
#define MAX_NB 1024
#define GCHUNK 1024           // entries per LDS pass (gather)
typedef unsigned int u32;

__global__ void __launch_bounds__(256)
k_zero_u32(u32* __restrict__ p, int n) {
    int i = blockIdx.x * blockDim.x + threadIdx.x;
    if (i < n) p[i] = 0u;
}

// Per-block bucket histogram -> hist[block][bucket]; totals via fire-and-forget atomics.
__global__ void __launch_bounds__(256)
k_hist(const int* __restrict__ dst, u32* __restrict__ hist,
       u32* __restrict__ total, int n_edges, int nb, int chunk) {
    __shared__ u32 h[MAX_NB];
    for (int i = threadIdx.x; i < nb; i += 256) h[i] = 0u;
    __syncthreads();
    int beg = blockIdx.x * chunk;
    int end = min(beg + chunk, n_edges);
    for (int e = beg + threadIdx.x; e < end; e += 256)
        atomicAdd(&h[((u32)dst[e]) >> BKT_SHIFT], 1u);
    __syncthreads();
    u32* row = hist + (size_t)blockIdx.x * nb;
    for (int i = threadIdx.x; i < nb; i += 256) {
        u32 v = h[i];
        row[i] = v;                       // coalesced
        if (v) atomicAdd(&total[i], v);   // no return-use -> throughput, not latency
    }
}

// Exclusive scan of bucket totals (nb <= 1024), one block.
__global__ void __launch_bounds__(1024)
k_scan(const u32* __restrict__ total, u32* __restrict__ offs, int nb, u32 tot) {
    __shared__ u32 s[1024];
    int t = threadIdx.x;
    u32 v = (t < nb) ? total[t] : 0u;
    s[t] = v;
    __syncthreads();
    for (int off = 1; off < 1024; off <<= 1) {
        u32 y = (t >= off) ? s[t - off] : 0u;
        __syncthreads();
        if (t >= off) s[t] += y;
        __syncthreads();
    }
    if (t < nb) offs[t] = s[t] - v;
    if (t == 0) offs[nb] = tot;
}

// Per-bucket prefix over blocks (nblk <= 1024): hist[j][b] <- offs[b] + prefix.
__global__ void __launch_bounds__(1024)
k_rank(u32* __restrict__ hist, const u32* __restrict__ offs, int nb, int nblk) {
    __shared__ u32 s[1024];
    int b = blockIdx.x, t = threadIdx.x;
    u32 v = (t < nblk) ? hist[(size_t)t * nb + b] : 0u;
    s[t] = v;
    __syncthreads();
    for (int off = 1; off < 1024; off <<= 1) {
        u32 y = (t >= off) ? s[t - off] : 0u;
        __syncthreads();
        if (t >= off) s[t] += y;
        __syncthreads();
    }
    if (t < nblk) hist[(size_t)t * nb + b] = offs[b] + s[t] - v;
}

// Placement into block-private contiguous runs; LDS-only RMW.
__global__ void __launch_bounds__(256)
k_scatter(const int* __restrict__ src, const int* __restrict__ dst,
          const u32* __restrict__ hist, u32* __restrict__ bin,
          int n_edges, int nb, int chunk) {
    __shared__ u32 cur[MAX_NB];
    const u32* row = hist + (size_t)blockIdx.x * nb;
    for (int i = threadIdx.x; i < nb; i += 256) cur[i] = row[i];
    __syncthreads();
    int beg = blockIdx.x * chunk;
    int end = min(beg + chunk, n_edges);
    for (int e = beg + threadIdx.x; e < end; e += 256) {
        u32 d = (u32)dst[e];
        u32 pos = atomicAdd(&cur[d >> BKT_SHIFT], 1u);
        bin[pos] = (u32)src[e] | ((d & (BKT_NODES - 1)) << 17);
    }
}

// 4 sub-blocks per bucket; sub-block sq handles nodes [sq*32, sq*32+32).
// Per 1024-entry pass: filter+count, 32-scan, rank into s_srt, then 256
// (node,q) tasks register-accumulate; 8 lanes = one aligned 128B x-row.
__global__ void __launch_bounds__(256)
k_gather(const float* __restrict__ x, const u32* __restrict__ offs,
         const u32* __restrict__ bin, float* __restrict__ out, int n_nodes) {
    __shared__ u32 s_ent[GCHUNK];
    __shared__ u32 s_srt[GCHUNK];
    __shared__ u32 s_off[33];
    __shared__ u32 s_cur[32];
    __shared__ u32 s_scan[32];
    int b  = blockIdx.x >> 2;
    int sq = blockIdx.x & 3;
    int t  = threadIdx.x;
    int node0 = b * BKT_NODES + sq * 32;
    if (node0 >= n_nodes) return;                 // uniform per block
    u32 beg = offs[b], end = offs[b + 1];
    const float4* x4 = (const float4*)x;
    int node = t >> 3, q = t & 7;
    float4 acc = make_float4(0.f, 0.f, 0.f, 0.f);

    for (u32 c0 = beg; c0 < end; c0 += GCHUNK) {
        int m = (int)min((u32)GCHUNK, end - c0);
        for (int i = t; i < m; i += 256) s_ent[i] = bin[c0 + i];
        if (t < 32) s_cur[t] = 0u;
        __syncthreads();
        for (int i = t; i < m; i += 256) {
            u32 dl = s_ent[i] >> 17;
            if ((int)(dl >> 5) == sq) atomicAdd(&s_cur[dl & 31], 1u);
        }
        __syncthreads();
        u32 v = 0u;
        if (t < 32) { v = s_cur[t]; s_scan[t] = v; }
        __syncthreads();
        for (int off = 1; off < 32; off <<= 1) {
            u32 y = 0u;
            if (t < 32 && t >= off) y = s_scan[t - off];
            __syncthreads();
            if (t < 32 && t >= off) s_scan[t] += y;
            __syncthreads();
        }
        if (t < 32) { u32 ex = s_scan[t] - v; s_off[t] = ex; s_cur[t] = ex; }
        if (t == 31) s_off[32] = s_scan[31];
        __syncthreads();
        for (int i = t; i < m; i += 256) {
            u32 p = s_ent[i];
            u32 dl = p >> 17;
            if ((int)(dl >> 5) == sq) {
                u32 pos = atomicAdd(&s_cur[dl & 31], 1u);
                s_srt[pos] = p & 0x1FFFFu;
            }
        }
        __syncthreads();
        u32 j1 = s_off[node + 1];
        for (u32 j = s_off[node]; j < j1; ++j) {
            float4 xv = x4[(size_t)s_srt[j] * 8 + q];   // LDS broadcast to 8 lanes
            acc.x += xv.x; acc.y += xv.y; acc.z += xv.z; acc.w += xv.w;
        }
        __syncthreads();
    }

    if (node0 + node < n_nodes)
        ((float4*)out)[(size_t)node0 * 8 + t] = acc;    // fully contiguous
}

// ---------------- fallback (round-1 atomic path) ----------------

__global__ void __launch_bounds__(256)
mp_zero_kernel(float* __restrict__ out, int n) {
    int i = blockIdx.x * blockDim.x + threadIdx.x;
    if (i < n) out[i] = 0.0f;
}

__global__ void __launch_bounds__(256)
mp_scatter_kernel(const float* __restrict__ x, const int* __restrict__ src,
                  const int* __restrict__ dst, float* __restrict__ out,
                  int n_edges) {
    int idx = blockIdx.x * blockDim.x + threadIdx.x;
    if (idx >= n_edges * 8) return;
    int e = idx >> 3;
    int c = idx & 7;
    const float4 v = *reinterpret_cast<const float4*>(x + (size_t)src[e] * D_FEAT + c * 4);
    float* o = out + (size_t)dst[e] * D_FEAT + c * 4;
    unsafeAtomicAdd(o + 0, v.x);
    unsafeAtomicAdd(o + 1, v.y);
    unsafeAtomicAdd(o + 2, v.z);
    unsafeAtomicAdd(o + 3, v.w);
}

// ---------------- launch ----------------

extern "C" void kernel_launch(void* const* d_in, const int* in_sizes, int n_in,
                              void* d_out, int out_size, void* d_ws, size_t ws_size,
                              hipStream_t stream) {
    const float* x = (const float*)d_in[0];
    const int* edge_index = (const int*)d_in[1];
    int n_edges = in_sizes[1] / 2;
    const int* src = edge_index;            // row 0: source j
    const int* dst = edge_index + n_edges;  // row 1: target i
    float* out = (float*)d_out;
    int n_nodes = out_size / D_FEAT;

    int nb = (n_nodes + BKT_NODES - 1) >> BKT_SHIFT;     // 782

    // Pick the smallest chunk (most blocks) whose hist matrix fits in ws.
    int chunk = 0, nblk = 0;
    size_t need = 0;
    const int cand[3] = {2048, 4096, 8192};
    for (int ci = 0; ci < 3; ++ci) {
        int c = cand[ci];
        int nbk = (n_edges + c - 1) / c;
        size_t nd = ((size_t)nbk * nb + nb + (nb + 1) + n_edges) * sizeof(u32);
        if (nd <= ws_size && nbk <= 1024) { chunk = c; nblk = nbk; need = nd; break; }
    }
    bool ok = (chunk != 0) && (nb <= MAX_NB) && (n_nodes <= (1 << 17));
    if (!ok) {
        mp_zero_kernel<<<(out_size + 255) / 256, 256, 0, stream>>>(out, out_size);
        int total_thr = n_edges * 8;
        mp_scatter_kernel<<<(total_thr + 255) / 256, 256, 0, stream>>>(x, src, dst, out, n_edges);
        return;
    }
    (void)need;

    u32* hist  = (u32*)d_ws;
    u32* total = hist + (size_t)nblk * nb;
    u32* offs  = total + nb;
    u32* bin   = offs + (nb + 1);

    k_zero_u32<<<(nb + 255) / 256, 256, 0, stream>>>(total, nb);
    k_hist<<<nblk, 256, 0, stream>>>(dst, hist, total, n_edges, nb, chunk);
    k_scan<<<1, 1024, 0, stream>>>(total, offs, nb, (u32)n_edges);
    k_rank<<<nb, 1024, 0, stream>>>(hist, offs, nb, nblk);
    k_scatter<<<nblk, 256, 0, stream>>>(src, dst, hist, bin, n_edges, nb, chunk);
    k_gather<<<nb * 4, 256, 0, stream>>>(x, offs, bin, out, n_nodes);
}

// Round 6
// 146.843 us; speedup vs baseline: 1.2202x; 1.2202x over previous
//
#include <hip/hip_runtime.h>

// out[d] = sum_{e: dst[e]==d} x[src[e]]   (N=100k, E=1.6M, D=32 f32)
//
// Round-5 lessons: (a) 4-way gather split duplicated the LDS sort and re-read
// bin 4x -> only 8% gain; fix with ONE 512-thread block per bucket instead.
// (b) k_rank's strided column reads (39 MB) + 612K hist atomics bloated the
// partition phases; fix with a coalesced 2-level tile scan (thread=bucket,
// loop over j) and no global atomics anywhere.

#define D_FEAT 32
#define BKT_SHIFT 7
#define BKT_NODES 128
#define MAX_NB 1024
#define NT 8                  // j-tiles for the 2-level rank scan
#define GCHUNK 2048           // entries per LDS pass (gather)
typedef unsigned int u32;

// Per-block bucket histogram -> hist[block][bucket]. Pure writes, coalesced.
__global__ void __launch_bounds__(256)
k_hist(const int* __restrict__ dst, u32* __restrict__ hist,
       int n_edges, int nb, int chunk) {
    __shared__ u32 h[MAX_NB];
    for (int i = threadIdx.x; i < nb; i += 256) h[i] = 0u;
    __syncthreads();
    int beg = blockIdx.x * chunk;
    int end = min(beg + chunk, n_edges);
    for (int e = beg + threadIdx.x; e < end; e += 256)
        atomicAdd(&h[((u32)dst[e]) >> BKT_SHIFT], 1u);
    __syncthreads();
    u32* row = hist + (size_t)blockIdx.x * nb;
    for (int i = threadIdx.x; i < nb; i += 256) row[i] = h[i];
}

// Tile scan: thread = bucket, loop j inside tile. In-place tile-local
// exclusive prefix along j; tilesum[jt][b] = tile total. Fully coalesced.
__global__ void __launch_bounds__(256)
k_tilescan(u32* __restrict__ hist, u32* __restrict__ tilesum,
           int nb, int nblk, int jtile) {
    int b = blockIdx.x * 256 + threadIdx.x;
    if (b >= nb) return;
    int jt = blockIdx.y;
    int j0 = jt * jtile, j1 = min(j0 + jtile, nblk);
    u32 run = 0u;
    for (int j = j0; j < j1; ++j) {
        u32 v = hist[(size_t)j * nb + b];
        hist[(size_t)j * nb + b] = run;
        run += v;
    }
    tilesum[(size_t)jt * nb + b] = run;
}

// Bucket scan (1 block): scan tilesums per bucket, LDS-scan bucket totals
// -> offs; fold offs into tilesum so scatter cursors = hist + tilesum.
__global__ void __launch_bounds__(1024)
k_bucketscan(u32* __restrict__ tilesum, u32* __restrict__ offs,
             int nb, int ntiles, u32 total_edges) {
    __shared__ u32 s[1024];
    int t = threadIdx.x;
    u32 run = 0u;
    if (t < nb) {
        for (int jt = 0; jt < ntiles; ++jt) {
            u32 v = tilesum[(size_t)jt * nb + t];
            tilesum[(size_t)jt * nb + t] = run;
            run += v;
        }
    }
    s[t] = (t < nb) ? run : 0u;
    __syncthreads();
    for (int off = 1; off < 1024; off <<= 1) {
        u32 y = (t >= off) ? s[t - off] : 0u;
        __syncthreads();
        if (t >= off) s[t] += y;
        __syncthreads();
    }
    if (t < nb) {
        u32 ex = s[t] - run;   // exclusive bucket base
        offs[t] = ex;
        for (int jt = 0; jt < ntiles; ++jt)
            tilesum[(size_t)jt * nb + t] += ex;
    }
    if (t == 0) offs[nb] = total_edges;
}

// Placement into block-private contiguous runs; LDS-only RMW; cursor bases
// from two coalesced reads.
__global__ void __launch_bounds__(256)
k_scatter(const int* __restrict__ src, const int* __restrict__ dst,
          const u32* __restrict__ hist, const u32* __restrict__ tilesum,
          u32* __restrict__ bin, int n_edges, int nb, int chunk, int jtile) {
    __shared__ u32 cur[MAX_NB];
    int j = blockIdx.x;
    int jt = j / jtile;
    const u32* row = hist + (size_t)j * nb;
    const u32* ts  = tilesum + (size_t)jt * nb;
    for (int i = threadIdx.x; i < nb; i += 256) cur[i] = row[i] + ts[i];
    __syncthreads();
    int beg = j * chunk;
    int end = min(beg + chunk, n_edges);
    for (int e = beg + threadIdx.x; e < end; e += 256) {
        u32 d = (u32)dst[e];
        u32 pos = atomicAdd(&cur[d >> BKT_SHIFT], 1u);
        bin[pos] = (u32)src[e] | ((d & (BKT_NODES - 1)) << 17);
    }
}

// One 512-thread block per bucket. Per 2048-entry pass: LDS count/scan/rank
// by dlocal, then each thread register-accumulates (node,q) and (node+64,q);
// 8 lanes fetch one aligned 128B x-row.
__global__ void __launch_bounds__(512)
k_gather(const float* __restrict__ x, const u32* __restrict__ offs,
         const u32* __restrict__ bin, float* __restrict__ out, int n_nodes) {
    __shared__ u32 s_ent[GCHUNK];
    __shared__ u32 s_srt[GCHUNK];
    __shared__ u32 s_off[BKT_NODES + 1];
    __shared__ u32 s_cur[BKT_NODES];
    __shared__ u32 s_scan[BKT_NODES];
    int b = blockIdx.x, t = threadIdx.x;
    int node0 = b * BKT_NODES;
    u32 beg = offs[b], end = offs[b + 1];
    const float4* x4 = (const float4*)x;
    int q = t & 7;
    int n0 = t >> 3;                       // 0..63; second node = n0+64
    float4 a0 = make_float4(0.f, 0.f, 0.f, 0.f);
    float4 a1 = make_float4(0.f, 0.f, 0.f, 0.f);

    for (u32 c0 = beg; c0 < end; c0 += GCHUNK) {
        int m = (int)min((u32)GCHUNK, end - c0);
        for (int i = t; i < m; i += 512) s_ent[i] = bin[c0 + i];
        if (t < BKT_NODES) s_cur[t] = 0u;
        __syncthreads();
        for (int i = t; i < m; i += 512) atomicAdd(&s_cur[s_ent[i] >> 17], 1u);
        __syncthreads();
        u32 v = 0u;
        if (t < BKT_NODES) { v = s_cur[t]; s_scan[t] = v; }
        __syncthreads();
        for (int off = 1; off < BKT_NODES; off <<= 1) {
            u32 y = 0u;
            if (t < BKT_NODES && t >= off) y = s_scan[t - off];
            __syncthreads();
            if (t < BKT_NODES && t >= off) s_scan[t] += y;
            __syncthreads();
        }
        if (t < BKT_NODES) { u32 ex = s_scan[t] - v; s_off[t] = ex; s_cur[t] = ex; }
        if (t == BKT_NODES - 1) s_off[BKT_NODES] = s_scan[BKT_NODES - 1];
        __syncthreads();
        for (int i = t; i < m; i += 512) {
            u32 p = s_ent[i];
            u32 pos = atomicAdd(&s_cur[p >> 17], 1u);
            s_srt[pos] = p & 0x1FFFFu;
        }
        __syncthreads();
        {
            u32 j1 = s_off[n0 + 1];
            for (u32 j = s_off[n0]; j < j1; ++j) {
                float4 xv = x4[(size_t)s_srt[j] * 8 + q];
                a0.x += xv.x; a0.y += xv.y; a0.z += xv.z; a0.w += xv.w;
            }
            u32 j3 = s_off[n0 + 65];
            for (u32 j = s_off[n0 + 64]; j < j3; ++j) {
                float4 xv = x4[(size_t)s_srt[j] * 8 + q];
                a1.x += xv.x; a1.y += xv.y; a1.z += xv.z; a1.w += xv.w;
            }
        }
        __syncthreads();
    }

    float4* o4 = (float4*)out;
    if (node0 + n0 < n_nodes)      o4[(size_t)node0 * 8 + t] = a0;        // contiguous
    if (node0 + n0 + 64 < n_nodes) o4[(size_t)node0 * 8 + 512 + t] = a1;  // contiguous
}

// ---------------- fallback (round-1 atomic path) ----------------

__global__ void __launch_bounds__(256)
mp_zero_kernel(float* __restrict__ out, int n) {
    int i = blockIdx.x * blockDim.x + threadIdx.x;
    if (i < n) out[i] = 0.0f;
}

__global__ void __launch_bounds__(256)
mp_scatter_kernel(const float* __restrict__ x, const int* __restrict__ src,
                  const int* __restrict__ dst, float* __restrict__ out,
                  int n_edges) {
    int idx = blockIdx.x * blockDim.x + threadIdx.x;
    if (idx >= n_edges * 8) return;
    int e = idx >> 3;
    int c = idx & 7;
    const float4 v = *reinterpret_cast<const float4*>(x + (size_t)src[e] * D_FEAT + c * 4);
    float* o = out + (size_t)dst[e] * D_FEAT + c * 4;
    unsafeAtomicAdd(o + 0, v.x);
    unsafeAtomicAdd(o + 1, v.y);
    unsafeAtomicAdd(o + 2, v.z);
    unsafeAtomicAdd(o + 3, v.w);
}

// ---------------- launch ----------------

extern "C" void kernel_launch(void* const* d_in, const int* in_sizes, int n_in,
                              void* d_out, int out_size, void* d_ws, size_t ws_size,
                              hipStream_t stream) {
    const float* x = (const float*)d_in[0];
    const int* edge_index = (const int*)d_in[1];
    int n_edges = in_sizes[1] / 2;
    const int* src = edge_index;            // row 0: source j
    const int* dst = edge_index + n_edges;  // row 1: target i
    float* out = (float*)d_out;
    int n_nodes = out_size / D_FEAT;

    int nb = (n_nodes + BKT_NODES - 1) >> BKT_SHIFT;     // 782

    // Pick smallest chunk whose hist matrix fits ws: 4096 preferred, else 8192.
    int chunk = 0, nblk = 0;
    const int cand[2] = {4096, 8192};
    for (int ci = 0; ci < 2; ++ci) {
        int c = cand[ci];
        int nbk = (n_edges + c - 1) / c;
        size_t nd = ((size_t)nbk * nb + (size_t)NT * nb + (nb + 1) + n_edges) * sizeof(u32);
        if (nd <= ws_size && nbk <= 4096) { chunk = c; nblk = nbk; break; }
    }
    bool ok = (chunk != 0) && (nb <= MAX_NB) && (n_nodes <= (1 << 17));
    if (!ok) {
        mp_zero_kernel<<<(out_size + 255) / 256, 256, 0, stream>>>(out, out_size);
        int total_thr = n_edges * 8;
        mp_scatter_kernel<<<(total_thr + 255) / 256, 256, 0, stream>>>(x, src, dst, out, n_edges);
        return;
    }

    u32* hist    = (u32*)d_ws;
    u32* tilesum = hist + (size_t)nblk * nb;
    u32* offs    = tilesum + (size_t)NT * nb;
    u32* bin     = offs + (nb + 1);

    int jtile = (nblk + NT - 1) / NT;

    dim3 tsgrid((nb + 255) / 256, NT);

    k_hist<<<nblk, 256, 0, stream>>>(dst, hist, n_edges, nb, chunk);
    k_tilescan<<<tsgrid, 256, 0, stream>>>(hist, tilesum, nb, nblk, jtile);
    k_bucketscan<<<1, 1024, 0, stream>>>(tilesum, offs, nb, NT, (u32)n_edges);
    k_scatter<<<nblk, 256, 0, stream>>>(src, dst, hist, tilesum, bin,
                                        n_edges, nb, chunk, jtile);
    k_gather<<<nb, 512, 0, stream>>>(x, offs, bin, out, n_nodes);
}